// Round 1
// baseline (469.519 us; speedup 1.0000x reference)
//
#include <hip/hip_runtime.h>
#include <cstddef>

#define BB 32
#define NN 512
#define FIN 64
#define F1 256   // H*HID
#define NH 4
#define FOUT 64
#define NEG_SLOPE 0.2f

// ---------------- K1: adj -> transposed bitmask (mask[b][d] bit s = edge s->d | s==d)
__global__ __launch_bounds__(256) void k_mask(const int* __restrict__ adj,
                                              unsigned* __restrict__ mask) {
  int b = blockIdx.x >> 1;
  int d = ((blockIdx.x & 1) << 8) | threadIdx.x;
  const int* ap = adj + (size_t)b * NN * NN + d;
  unsigned* mp = mask + ((size_t)b * NN + d) * 16;
  for (int k = 0; k < 16; ++k) {
    unsigned wv = 0;
#pragma unroll
    for (int j = 0; j < 32; ++j) {
      int s = k * 32 + j;
      unsigned bit = ((ap[(size_t)s * NN] != 0) | (s == d)) ? 1u : 0u;
      wv |= bit << j;
    }
    mp[k] = wv;
  }
}

// ---------------- K2: h1 = x @ W1 ; e1s/e1d per (node, head)
__global__ __launch_bounds__(256) void k_gemm1(const float* __restrict__ x,
                                               const float* __restrict__ W1,
                                               const float* __restrict__ a1s,
                                               const float* __restrict__ a1d,
                                               float* __restrict__ h1,
                                               float* __restrict__ e1s,
                                               float* __restrict__ e1d) {
  __shared__ float xs[32 * FIN];  // 8 KB
  int b = blockIdx.x >> 4;
  int n0 = (blockIdx.x & 15) * 32;
  int f = threadIdx.x;  // 0..255 output feature
  const float4* xsrc = (const float4*)(x + ((size_t)b * NN + n0) * FIN);
  float4* xs4 = (float4*)xs;
  xs4[f] = xsrc[f];
  xs4[f + 256] = xsrc[f + 256];
  float wreg[64];
#pragma unroll
  for (int k = 0; k < 64; ++k) wreg[k] = W1[k * F1 + f];
  float asf = a1s[f], adf = a1d[f];
  int h = f >> 6, lane = f & 63;
  __syncthreads();
  for (int n = 0; n < 32; ++n) {
    const float4* xr = (const float4*)(xs + n * FIN);
    float acc = 0.f;
#pragma unroll
    for (int kk = 0; kk < 16; ++kk) {
      float4 xv = xr[kk];
      acc += xv.x * wreg[kk * 4] + xv.y * wreg[kk * 4 + 1] +
             xv.z * wreg[kk * 4 + 2] + xv.w * wreg[kk * 4 + 3];
    }
    h1[((size_t)b * NN + n0 + n) * F1 + f] = acc;
    float cs = acc * asf, cd = acc * adf;
#pragma unroll
    for (int off = 32; off > 0; off >>= 1) {
      cs += __shfl_down(cs, off, 64);
      cd += __shfl_down(cd, off, 64);
    }
    if (lane == 0) {
      e1s[((size_t)b * NN + n0 + n) * NH + h] = cs;
      e1d[((size_t)b * NN + n0 + n) * NH + h] = cd;
    }
  }
}

// ---------------- K3: layer-1 attention + aggregate + bias + ELU
__global__ __launch_bounds__(256) void k_attn1(const unsigned* __restrict__ mask,
                                               const float* __restrict__ h1,
                                               const float* __restrict__ e1s,
                                               const float* __restrict__ e1d,
                                               const float* __restrict__ b1,
                                               float* __restrict__ h1a) {
  __shared__ float es[NN * NH];        // 8 KB
  __shared__ unsigned mw[32 * 16];     // 2 KB
  __shared__ float pbuf[32 * NH * 32]; // [j][h][d] 16 KB
  __shared__ float pm[2 * 128], pl[2 * 128], linv[128];
  int b = blockIdx.x >> 4;
  int d0 = (blockIdx.x & 15) * 32;
  int t = threadIdx.x;
  const float* esrc = e1s + (size_t)b * NN * NH;
#pragma unroll
  for (int i = 0; i < 8; ++i) es[t + i * 256] = esrc[t + i * 256];
  const unsigned* msrc = mask + ((size_t)b * NN + d0) * 16;
  mw[t] = msrc[t];
  mw[t + 256] = msrc[t + 256];
  __syncthreads();

  int d = t & 31, h = (t >> 5) & 3, q = t >> 7;  // q: s-range half
  float ed = e1d[((size_t)b * NN + d0 + d) * NH + h];
  // pass 1: masked max over this thread's s-half
  float m = -3.0e38f;
  for (int k = q * 8; k < q * 8 + 8; ++k) {
    unsigned wv = mw[d * 16 + k];
#pragma unroll
    for (int j = 0; j < 32; ++j) {
      float sc = ed + es[(k * 32 + j) * NH + h];
      sc = fmaxf(sc, NEG_SLOPE * sc);
      sc = ((wv >> j) & 1) ? sc : -1e9f;
      m = fmaxf(m, sc);
    }
  }
  pm[q * 128 + h * 32 + d] = m;
  __syncthreads();
  m = fmaxf(pm[h * 32 + d], pm[128 + h * 32 + d]);  // merged max (same in both halves)
  // pass 2: sum of exp
  float l = 0.f;
  for (int k = q * 8; k < q * 8 + 8; ++k) {
    unsigned wv = mw[d * 16 + k];
#pragma unroll
    for (int j = 0; j < 32; ++j) {
      float sc = ed + es[(k * 32 + j) * NH + h];
      sc = fmaxf(sc, NEG_SLOPE * sc);
      l += ((wv >> j) & 1) ? __expf(sc - m) : 0.f;
    }
  }
  pl[q * 128 + h * 32 + d] = l;
  __syncthreads();
  if (q == 0) linv[h * 32 + d] = 1.f / (pl[h * 32 + d] + pl[128 + h * 32 + d]);

  // phase 2: tiles of 32 src
  int f = t;           // feature for role B
  int fh = f >> 6;
  int jq = q;          // j-half for role A
  float acc[32];
#pragma unroll
  for (int i = 0; i < 32; ++i) acc[i] = 0.f;
  __syncthreads();
  for (int tile = 0; tile < 16; ++tile) {
    // role A: p for j in [jq*16, jq*16+16)
    unsigned wv = mw[d * 16 + tile];
#pragma unroll
    for (int jj = 0; jj < 16; ++jj) {
      int j = jq * 16 + jj;
      float sc = ed + es[(tile * 32 + j) * NH + h];
      sc = fmaxf(sc, NEG_SLOPE * sc);
      pbuf[(j * NH + h) * 32 + d] = ((wv >> j) & 1) ? __expf(sc - m) : 0.f;
    }
    __syncthreads();
    // role B: accumulate 32 dst for feature f
    const float* hrow = h1 + ((size_t)b * NN + tile * 32) * F1 + f;
#pragma unroll 4
    for (int j = 0; j < 32; ++j) {
      float val = hrow[(size_t)j * F1];
      const float4* pr = (const float4*)&pbuf[(j * NH + fh) * 32];
#pragma unroll
      for (int dq = 0; dq < 8; ++dq) {
        float4 pv = pr[dq];
        acc[dq * 4 + 0] += pv.x * val;
        acc[dq * 4 + 1] += pv.y * val;
        acc[dq * 4 + 2] += pv.z * val;
        acc[dq * 4 + 3] += pv.w * val;
      }
    }
    __syncthreads();
  }
  float bf = b1[f];
#pragma unroll
  for (int dd = 0; dd < 32; ++dd) {
    float r = acc[dd] * linv[fh * 32 + dd] + bf;
    r = (r > 0.f) ? r : (__expf(r) - 1.f);  // ELU(alpha=1)
    h1a[((size_t)b * NN + d0 + dd) * F1 + f] = r;
  }
}

// ---------------- K4: h2 = h1a @ W2 ; e2s/e2d per node
__global__ __launch_bounds__(256) void k_gemm2(const float* __restrict__ h1a,
                                               const float* __restrict__ W2,
                                               const float* __restrict__ a2s,
                                               const float* __restrict__ a2d,
                                               float* __restrict__ h2,
                                               float* __restrict__ e2s,
                                               float* __restrict__ e2d) {
  __shared__ float hs[32 * F1];  // 32 KB
  int b = blockIdx.x >> 4;
  int n0 = (blockIdx.x & 15) * 32;
  int t = threadIdx.x;
  const float4* src = (const float4*)(h1a + ((size_t)b * NN + n0) * F1);
  float4* hs4 = (float4*)hs;
#pragma unroll
  for (int i = 0; i < 8; ++i) hs4[t + i * 256] = src[t + i * 256];
  int f = t & 63, nq = t >> 6;  // nq: node quarter (8 nodes each)
  float acc[8];
#pragma unroll
  for (int i = 0; i < 8; ++i) acc[i] = 0.f;
  __syncthreads();
  for (int kc = 0; kc < 4; ++kc) {
    float wreg[64];
#pragma unroll
    for (int kk = 0; kk < 64; ++kk) wreg[kk] = W2[(kc * 64 + kk) * FOUT + f];
#pragma unroll
    for (int n = 0; n < 8; ++n) {
      const float4* hr = (const float4*)(hs + (nq * 8 + n) * F1 + kc * 64);
      float a = acc[n];
#pragma unroll
      for (int kk = 0; kk < 16; ++kk) {
        float4 hv = hr[kk];
        a += hv.x * wreg[kk * 4] + hv.y * wreg[kk * 4 + 1] +
             hv.z * wreg[kk * 4 + 2] + hv.w * wreg[kk * 4 + 3];
      }
      acc[n] = a;
    }
  }
  float asf = a2s[f], adf = a2d[f];
#pragma unroll
  for (int n = 0; n < 8; ++n) {
    int node = n0 + nq * 8 + n;
    h2[((size_t)b * NN + node) * FOUT + f] = acc[n];
    float cs = acc[n] * asf, cd = acc[n] * adf;
#pragma unroll
    for (int off = 32; off > 0; off >>= 1) {
      cs += __shfl_down(cs, off, 64);
      cd += __shfl_down(cd, off, 64);
    }
    if (f == 0) {
      e2s[(size_t)b * NN + node] = cs;
      e2d[(size_t)b * NN + node] = cd;
    }
  }
}

// ---------------- K5: layer-2 attention + aggregate + bias -> out
__global__ __launch_bounds__(256) void k_attn2(const unsigned* __restrict__ mask,
                                               const float* __restrict__ h2,
                                               const float* __restrict__ e2s,
                                               const float* __restrict__ e2d,
                                               const float* __restrict__ b2,
                                               float* __restrict__ out) {
  __shared__ float es[NN];          // 2 KB
  __shared__ unsigned mw[32 * 16];  // 2 KB
  __shared__ float pbuf[32 * 32];   // [j][d] 4 KB
  __shared__ float pm[8 * 32], pl[8 * 32], linv[32];
  int b = blockIdx.x >> 4;
  int d0 = (blockIdx.x & 15) * 32;
  int t = threadIdx.x;
  es[t] = e2s[(size_t)b * NN + t];
  es[t + 256] = e2s[(size_t)b * NN + t + 256];
  const unsigned* msrc = mask + ((size_t)b * NN + d0) * 16;
  mw[t] = msrc[t];
  mw[t + 256] = msrc[t + 256];
  __syncthreads();

  int d = t & 31, q = t >> 5;  // q: s-range eighth (64 src each)
  float ed = e2d[(size_t)b * NN + d0 + d];
  float m = -3.0e38f;
  for (int k = q * 2; k < q * 2 + 2; ++k) {
    unsigned wv = mw[d * 16 + k];
#pragma unroll
    for (int j = 0; j < 32; ++j) {
      float sc = ed + es[k * 32 + j];
      sc = fmaxf(sc, NEG_SLOPE * sc);
      sc = ((wv >> j) & 1) ? sc : -1e9f;
      m = fmaxf(m, sc);
    }
  }
  pm[q * 32 + d] = m;
  __syncthreads();
  m = pm[d];
#pragma unroll
  for (int i = 1; i < 8; ++i) m = fmaxf(m, pm[i * 32 + d]);
  float l = 0.f;
  for (int k = q * 2; k < q * 2 + 2; ++k) {
    unsigned wv = mw[d * 16 + k];
#pragma unroll
    for (int j = 0; j < 32; ++j) {
      float sc = ed + es[k * 32 + j];
      sc = fmaxf(sc, NEG_SLOPE * sc);
      l += ((wv >> j) & 1) ? __expf(sc - m) : 0.f;
    }
  }
  pl[q * 32 + d] = l;
  __syncthreads();
  if (q == 0) {
    float lt = 0.f;
#pragma unroll
    for (int i = 0; i < 8; ++i) lt += pl[i * 32 + d];
    linv[d] = 1.f / lt;
  }

  int f = t & 63, dg = t >> 6;  // role B: 8 dst each
  int jq = q;                   // role A: 4 j each
  float acc[8];
#pragma unroll
  for (int i = 0; i < 8; ++i) acc[i] = 0.f;
  __syncthreads();
  for (int tile = 0; tile < 16; ++tile) {
    unsigned wv = mw[d * 16 + tile];
#pragma unroll
    for (int jj = 0; jj < 4; ++jj) {
      int j = jq * 4 + jj;
      float sc = ed + es[tile * 32 + j];
      sc = fmaxf(sc, NEG_SLOPE * sc);
      pbuf[j * 32 + d] = ((wv >> j) & 1) ? __expf(sc - m) : 0.f;
    }
    __syncthreads();
    const float* hrow = h2 + ((size_t)b * NN + tile * 32) * FOUT + f;
#pragma unroll 4
    for (int j = 0; j < 32; ++j) {
      float val = hrow[(size_t)j * FOUT];
      const float4* pr = (const float4*)&pbuf[j * 32 + dg * 8];
      float4 p0 = pr[0], p1 = pr[1];
      acc[0] += p0.x * val;
      acc[1] += p0.y * val;
      acc[2] += p0.z * val;
      acc[3] += p0.w * val;
      acc[4] += p1.x * val;
      acc[5] += p1.y * val;
      acc[6] += p1.z * val;
      acc[7] += p1.w * val;
    }
    __syncthreads();
  }
  float bf = b2[f];
#pragma unroll
  for (int i = 0; i < 8; ++i) {
    int dd = dg * 8 + i;
    out[((size_t)b * NN + d0 + dd) * FOUT + f] = acc[i] * linv[dd] + bf;
  }
}

extern "C" void kernel_launch(void* const* d_in, const int* in_sizes, int n_in,
                              void* d_out, int out_size, void* d_ws, size_t ws_size,
                              hipStream_t stream) {
  const float* x = (const float*)d_in[0];
  const int* adj = (const int*)d_in[1];
  const float* W1 = (const float*)d_in[2];
  const float* a1s = (const float*)d_in[3];
  const float* a1d = (const float*)d_in[4];
  const float* b1 = (const float*)d_in[5];
  const float* W2 = (const float*)d_in[6];
  const float* a2s = (const float*)d_in[7];
  const float* a2d = (const float*)d_in[8];
  const float* b2 = (const float*)d_in[9];
  float* out = (float*)d_out;

  char* w = (char*)d_ws;
  unsigned* mask = (unsigned*)w;                            // 1 MB
  float* h1 = (float*)(w + (1u << 20));                     // 16 MB
  float* h1a = (float*)(w + (17u << 20));                   // 16 MB
  float* h2 = (float*)(w + (33u << 20));                    // 4 MB
  float* e1s = (float*)(w + (37u << 20));                   // 256 KB
  float* e1d = (float*)(w + (37u << 20) + (256u << 10));    // 256 KB
  float* e2s = (float*)(w + (37u << 20) + (512u << 10));    // 64 KB
  float* e2d = (float*)(w + (37u << 20) + (576u << 10));    // 64 KB

  hipLaunchKernelGGL(k_mask, dim3(64), dim3(256), 0, stream, adj, mask);
  hipLaunchKernelGGL(k_gemm1, dim3(512), dim3(256), 0, stream, x, W1, a1s, a1d,
                     h1, e1s, e1d);
  hipLaunchKernelGGL(k_attn1, dim3(512), dim3(256), 0, stream, mask, h1, e1s,
                     e1d, b1, h1a);
  hipLaunchKernelGGL(k_gemm2, dim3(512), dim3(256), 0, stream, h1a, W2, a2s,
                     a2d, h2, e2s, e2d);
  hipLaunchKernelGGL(k_attn2, dim3(512), dim3(256), 0, stream, mask, h2, e2s,
                     e2d, b2, out);
}

// Round 2
// 167.730 us; speedup vs baseline: 2.7993x; 2.7993x over previous
//
#include <hip/hip_runtime.h>
#include <cstddef>

#define NN 512
#define NEG_SLOPE 0.2f

typedef __attribute__((ext_vector_type(8))) short short8;
typedef __attribute__((ext_vector_type(16))) float f32x16;

__device__ __forceinline__ unsigned short f2bf(float v) {
  unsigned u = __float_as_uint(v);
  return (unsigned short)((u + 0x7FFFu + ((u >> 16) & 1u)) >> 16);
}

// ---------------- K1: adj -> bitmask, layout mask[b][w][d], bit j of word w = edge (s=w*32+j)->d | s==d
__global__ __launch_bounds__(256) void k_mask(const int* __restrict__ adj,
                                              unsigned* __restrict__ mask) {
  int b = blockIdx.x >> 4;
  int w = blockIdx.x & 15;
  const int* base = adj + (size_t)b * NN * NN + (size_t)w * 32 * NN;
#pragma unroll
  for (int half = 0; half < 2; ++half) {
    int d = threadIdx.x + half * 256;
    unsigned wv = 0;
#pragma unroll
    for (int j = 0; j < 32; ++j) {
      unsigned bit = ((base[(size_t)j * NN + d] != 0) || (w * 32 + j == d)) ? 1u : 0u;
      wv |= bit << j;
    }
    mask[((size_t)b * 16 + w) * NN + d] = wv;
  }
}

// ---------------- K2: h1 = x @ W1 (written as bf16 B-fragments for 32x32x16 MFMA) ; e1s/e1d [h][node]
__global__ __launch_bounds__(256) void k_gemm1(const float* __restrict__ x,
                                               const float* __restrict__ W1,
                                               const float* __restrict__ a1s,
                                               const float* __restrict__ a1d,
                                               unsigned short* __restrict__ hb1,
                                               float* __restrict__ e1s,
                                               float* __restrict__ e1d) {
  __shared__ float xs[32 * 64];  // 8 KB
  int b = blockIdx.x >> 4;
  int n0 = (blockIdx.x & 15) * 32;
  int t = threadIdx.x;
  const float4* xsrc = (const float4*)(x + ((size_t)b * NN + n0) * 64);
  float4* xs4 = (float4*)xs;
  xs4[t] = xsrc[t];
  xs4[t + 256] = xsrc[t + 256];
  float wreg[64];
#pragma unroll
  for (int k = 0; k < 64; ++k) wreg[k] = W1[k * 256 + t];
  float asf = a1s[t], adf = a1d[t];
  int h = t >> 6, nf = t & 63;
  __syncthreads();
  for (int g = 0; g < 4; ++g) {
    float accv[8];
#pragma unroll
    for (int i = 0; i < 8; ++i) {
      int n = g * 8 + i;
      const float4* xr = (const float4*)(xs + n * 64);
      float acc = 0.f;
#pragma unroll
      for (int kk = 0; kk < 16; ++kk) {
        float4 xv = xr[kk];
        acc += xv.x * wreg[kk * 4] + xv.y * wreg[kk * 4 + 1] +
               xv.z * wreg[kk * 4 + 2] + xv.w * wreg[kk * 4 + 3];
      }
      accv[i] = acc;
      float cs = acc * asf, cd = acc * adf;
#pragma unroll
      for (int off = 32; off > 0; off >>= 1) {
        cs += __shfl_down(cs, off, 64);
        cd += __shfl_down(cd, off, 64);
      }
      if (nf == 0) {
        e1s[((size_t)b * 4 + h) * NN + n0 + n] = cs;
        e1d[((size_t)b * 4 + h) * NN + n0 + n] = cd;
      }
    }
    // pack 8 nodes (j=0..7 of one B-fragment) as bf16 and store 16B coalesced
    int kt = (n0 + g * 8) >> 4;  // s>>4
    int lg = g & 1;              // (s>>3)&1
    uint4 hi;
    unsigned* hp = (unsigned*)&hi;
#pragma unroll
    for (int i2 = 0; i2 < 4; ++i2)
      hp[i2] = (unsigned)f2bf(accv[2 * i2]) | ((unsigned)f2bf(accv[2 * i2 + 1]) << 16);
    size_t fidx = ((((size_t)b * 4 + h) * 32 + kt) * 2 + (nf >> 5)) * 64 + lg * 32 + (nf & 31);
    ((uint4*)hb1)[fidx] = hi;
  }
}

// ---------------- K3: layer-1 attention via MFMA. Block = (b, 32 dst); wave = head.
__global__ __launch_bounds__(256) void k_attn1(const unsigned* __restrict__ mask,
                                               const unsigned short* __restrict__ hb1,
                                               const float* __restrict__ e1s,
                                               const float* __restrict__ e1d,
                                               const float* __restrict__ b1,
                                               float* __restrict__ h1a) {
  __shared__ float es[4 * NN];      // 8 KB, [h][k]
  __shared__ unsigned mw[16 * 32];  // 2 KB, [w][d]
  int b = blockIdx.x >> 4;
  int d0 = (blockIdx.x & 15) * 32;
  int t = threadIdx.x;
  const float* esrc = e1s + (size_t)b * 4 * NN;
#pragma unroll
  for (int i = 0; i < 8; ++i) es[t + i * 256] = esrc[t + i * 256];
  const unsigned* msrc = mask + (size_t)b * 16 * NN + d0;
  mw[t] = msrc[(t >> 5) * NN + (t & 31)];
  {
    int idx = t + 256;
    mw[idx] = msrc[(idx >> 5) * NN + (idx & 31)];
  }
  __syncthreads();
  int h = t >> 6, lane = t & 63, m = lane & 31, kg = lane >> 5;
  float ed = e1d[((size_t)b * 4 + h) * NN + d0 + m];
  const short8* bfr = (const short8*)hb1 + ((size_t)b * 4 + h) * 32 * 2 * 64;
  f32x16 acc0, acc1;
#pragma unroll
  for (int i = 0; i < 16; ++i) { acc0[i] = 0.f; acc1[i] = 0.f; }
  float l = 0.f;
  for (int kt = 0; kt < 32; ++kt) {
    unsigned wv = mw[(kt >> 1) * 32 + m];
    int shift = (kt & 1) * 16 + kg * 8;
    const float* ep = &es[h * NN + kt * 16 + kg * 8];
    short8 a;
#pragma unroll
    for (int j = 0; j < 8; ++j) {
      float sc = ed + ep[j];
      sc = fmaxf(sc, NEG_SLOPE * sc);           // leaky_relu
      float pv = __expf(sc);                    // no max-shift needed: sc is O(+-8)
      pv = ((wv >> (shift + j)) & 1u) ? pv : 0.f;
      l += pv;
      a[j] = (short)f2bf(pv);
    }
    short8 bv0 = bfr[(kt * 2 + 0) * 64 + lane];
    short8 bv1 = bfr[(kt * 2 + 1) * 64 + lane];
    acc0 = __builtin_amdgcn_mfma_f32_32x32x16_bf16(a, bv0, acc0, 0, 0, 0);
    acc1 = __builtin_amdgcn_mfma_f32_32x32x16_bf16(a, bv1, acc1, 0, 0, 0);
  }
  float lf = l + __shfl(l, lane ^ 32, 64);  // combine the two k-half partials per dst
  float linv = 1.f / lf;
  float bia0 = b1[h * 64 + m];
  float bia1 = b1[h * 64 + 32 + m];
#pragma unroll
  for (int reg = 0; reg < 16; ++reg) {
    int row = (reg & 3) + 8 * (reg >> 2) + 4 * kg;  // C/D row map (m74/m101)
    float li = __shfl(linv, row, 64);
    float v0 = acc0[reg] * li + bia0;
    v0 = (v0 > 0.f) ? v0 : (__expf(v0) - 1.f);  // ELU
    float v1 = acc1[reg] * li + bia1;
    v1 = (v1 > 0.f) ? v1 : (__expf(v1) - 1.f);
    size_t rb = ((size_t)b * NN + d0 + row) * 256 + h * 64;
    h1a[rb + m] = v0;
    h1a[rb + 32 + m] = v1;
  }
}

// ---------------- K4: h2 = h1a @ W2 (bf16 B-fragments) ; e2s/e2d per node
__global__ __launch_bounds__(256) void k_gemm2(const float* __restrict__ h1a,
                                               const float* __restrict__ W2,
                                               const float* __restrict__ a2s,
                                               const float* __restrict__ a2d,
                                               unsigned short* __restrict__ hb2,
                                               float* __restrict__ e2s,
                                               float* __restrict__ e2d) {
  __shared__ float hs[32 * 256];  // 32 KB
  int b = blockIdx.x >> 4;
  int n0 = (blockIdx.x & 15) * 32;
  int t = threadIdx.x;
  const float4* src = (const float4*)(h1a + ((size_t)b * NN + n0) * 256);
  float4* hs4 = (float4*)hs;
#pragma unroll
  for (int i = 0; i < 8; ++i) hs4[t + i * 256] = src[t + i * 256];
  int f = t & 63, nq = t >> 6;  // 8 nodes per thread
  float acc[8];
#pragma unroll
  for (int i = 0; i < 8; ++i) acc[i] = 0.f;
  __syncthreads();
  for (int kc = 0; kc < 4; ++kc) {
    float wreg[64];
#pragma unroll
    for (int kk = 0; kk < 64; ++kk) wreg[kk] = W2[(kc * 64 + kk) * 64 + f];
#pragma unroll
    for (int n = 0; n < 8; ++n) {
      const float4* hr = (const float4*)(hs + (nq * 8 + n) * 256 + kc * 64);
      float a = acc[n];
#pragma unroll
      for (int kk = 0; kk < 16; ++kk) {
        float4 hv = hr[kk];
        a += hv.x * wreg[kk * 4] + hv.y * wreg[kk * 4 + 1] +
             hv.z * wreg[kk * 4 + 2] + hv.w * wreg[kk * 4 + 3];
      }
      acc[n] = a;
    }
  }
  float asf = a2s[f], adf = a2d[f];
#pragma unroll
  for (int n = 0; n < 8; ++n) {
    float cs = acc[n] * asf, cd = acc[n] * adf;
#pragma unroll
    for (int off = 32; off > 0; off >>= 1) {
      cs += __shfl_down(cs, off, 64);
      cd += __shfl_down(cd, off, 64);
    }
    if (f == 0) {
      e2s[(size_t)b * NN + n0 + nq * 8 + n] = cs;
      e2d[(size_t)b * NN + n0 + nq * 8 + n] = cd;
    }
  }
  int kt = (n0 >> 4) + (nq >> 1);
  int lg = nq & 1;
  uint4 hi;
  unsigned* hp = (unsigned*)&hi;
#pragma unroll
  for (int i2 = 0; i2 < 4; ++i2)
    hp[i2] = (unsigned)f2bf(acc[2 * i2]) | ((unsigned)f2bf(acc[2 * i2 + 1]) << 16);
  size_t fidx = (((size_t)b * 32 + kt) * 2 + (f >> 5)) * 64 + lg * 32 + (f & 31);
  ((uint4*)hb2)[fidx] = hi;
}

// ---------------- K5: layer-2 attention via MFMA, 4 waves split K, LDS reduce
__global__ __launch_bounds__(256) void k_attn2(const unsigned* __restrict__ mask,
                                               const unsigned short* __restrict__ hb2,
                                               const float* __restrict__ e2s,
                                               const float* __restrict__ e2d,
                                               const float* __restrict__ b2,
                                               float* __restrict__ out) {
  __shared__ float es[NN];          // 2 KB
  __shared__ unsigned mw[16 * 32];  // 2 KB
  __shared__ float cred[4][2][16][64];  // 32 KB
  __shared__ float lred[4][64];
  __shared__ float linv_s[32];
  int b = blockIdx.x >> 4;
  int d0 = (blockIdx.x & 15) * 32;
  int t = threadIdx.x;
  es[t] = e2s[(size_t)b * NN + t];
  es[t + 256] = e2s[(size_t)b * NN + t + 256];
  const unsigned* msrc = mask + (size_t)b * 16 * NN + d0;
  mw[t] = msrc[(t >> 5) * NN + (t & 31)];
  {
    int idx = t + 256;
    mw[idx] = msrc[(idx >> 5) * NN + (idx & 31)];
  }
  __syncthreads();
  int w = t >> 6, lane = t & 63, m = lane & 31, kg = lane >> 5;
  float ed = e2d[(size_t)b * NN + d0 + m];
  const short8* bfr = (const short8*)hb2 + (size_t)b * 32 * 2 * 64;
  f32x16 acc0, acc1;
#pragma unroll
  for (int i = 0; i < 16; ++i) { acc0[i] = 0.f; acc1[i] = 0.f; }
  float l = 0.f;
#pragma unroll
  for (int kk = 0; kk < 8; ++kk) {
    int kt = w * 8 + kk;
    unsigned wv = mw[(kt >> 1) * 32 + m];
    int shift = (kt & 1) * 16 + kg * 8;
    const float* ep = &es[kt * 16 + kg * 8];
    short8 a;
#pragma unroll
    for (int j = 0; j < 8; ++j) {
      float sc = ed + ep[j];
      sc = fmaxf(sc, NEG_SLOPE * sc);
      float pv = __expf(sc);
      pv = ((wv >> (shift + j)) & 1u) ? pv : 0.f;
      l += pv;
      a[j] = (short)f2bf(pv);
    }
    short8 bv0 = bfr[(kt * 2 + 0) * 64 + lane];
    short8 bv1 = bfr[(kt * 2 + 1) * 64 + lane];
    acc0 = __builtin_amdgcn_mfma_f32_32x32x16_bf16(a, bv0, acc0, 0, 0, 0);
    acc1 = __builtin_amdgcn_mfma_f32_32x32x16_bf16(a, bv1, acc1, 0, 0, 0);
  }
  lred[w][lane] = l;
#pragma unroll
  for (int reg = 0; reg < 16; ++reg) {
    cred[w][0][reg][lane] = acc0[reg];
    cred[w][1][reg][lane] = acc1[reg];
  }
  __syncthreads();
  if (t < 32) {
    float s = 0.f;
#pragma unroll
    for (int i = 0; i < 4; ++i) s += lred[i][t] + lred[i][t + 32];
    linv_s[t] = 1.f / s;
  }
  __syncthreads();
#pragma unroll
  for (int i = 0; i < 8; ++i) {
    int pos = t + i * 256;
    int nt = pos >> 10;
    int rem = pos & 1023;
    int reg = rem >> 6;
    int ln = rem & 63;
    float v = cred[0][nt][reg][ln] + cred[1][nt][reg][ln] +
              cred[2][nt][reg][ln] + cred[3][nt][reg][ln];
    int row = (reg & 3) + 8 * (reg >> 2) + 4 * (ln >> 5);
    int col = nt * 32 + (ln & 31);
    out[((size_t)b * NN + d0 + row) * 64 + col] = v * linv_s[row] + b2[col];
  }
}

extern "C" void kernel_launch(void* const* d_in, const int* in_sizes, int n_in,
                              void* d_out, int out_size, void* d_ws, size_t ws_size,
                              hipStream_t stream) {
  const float* x = (const float*)d_in[0];
  const int* adj = (const int*)d_in[1];
  const float* W1 = (const float*)d_in[2];
  const float* a1s = (const float*)d_in[3];
  const float* a1d = (const float*)d_in[4];
  const float* b1 = (const float*)d_in[5];
  const float* W2 = (const float*)d_in[6];
  const float* a2s = (const float*)d_in[7];
  const float* a2d = (const float*)d_in[8];
  const float* b2 = (const float*)d_in[9];
  float* out = (float*)d_out;

  char* w = (char*)d_ws;
  unsigned* mask = (unsigned*)w;                           // 1 MiB
  unsigned short* hb1 = (unsigned short*)(w + (1u << 20)); // 8 MiB
  unsigned short* hb2 = (unsigned short*)(w + (9u << 20)); // 2 MiB
  float* h1a = (float*)(w + (11u << 20));                  // 16 MiB
  float* e1s = (float*)(w + (27u << 20));                  // 256 KiB
  float* e1d = (float*)(w + (27u << 20) + (256u << 10));   // 256 KiB
  float* e2s = (float*)(w + (27u << 20) + (512u << 10));   // 64 KiB
  float* e2d = (float*)(w + (27u << 20) + (576u << 10));   // 64 KiB

  hipLaunchKernelGGL(k_mask, dim3(512), dim3(256), 0, stream, adj, mask);
  hipLaunchKernelGGL(k_gemm1, dim3(512), dim3(256), 0, stream, x, W1, a1s, a1d,
                     hb1, e1s, e1d);
  hipLaunchKernelGGL(k_attn1, dim3(512), dim3(256), 0, stream, mask, hb1, e1s,
                     e1d, b1, h1a);
  hipLaunchKernelGGL(k_gemm2, dim3(512), dim3(256), 0, stream, h1a, W2, a2s,
                     a2d, hb2, e2s, e2d);
  hipLaunchKernelGGL(k_attn2, dim3(512), dim3(256), 0, stream, mask, hb2, e2s,
                     e2d, b2, out);
}

// Round 3
// 147.390 us; speedup vs baseline: 3.1856x; 1.1380x over previous
//
#include <hip/hip_runtime.h>
#include <cstddef>

#define NN 512
#define NEG_SLOPE 0.2f

typedef __attribute__((ext_vector_type(8))) short short8;
typedef __attribute__((ext_vector_type(16))) float f32x16;

__device__ __forceinline__ unsigned short f2bf(float v) {
  unsigned u = __float_as_uint(v);
  return (unsigned short)((u + 0x7FFFu + ((u >> 16) & 1u)) >> 16);
}

// ---------------- K0: prep. blocks 0..511: adj->bitmask; 512..1023: x->A-frags;
// 1024..1032: W1(+wa1)->B-frags (9 n-tiles); 1033..1044: W2(+wa2)->B-frags (3 n-tiles)
__global__ __launch_bounds__(256) void k_prep(
    const int* __restrict__ adj, const float* __restrict__ x,
    const float* __restrict__ W1, const float* __restrict__ a1s,
    const float* __restrict__ a1d, const float* __restrict__ W2,
    const float* __restrict__ a2s, const float* __restrict__ a2d,
    unsigned* __restrict__ mask, short8* __restrict__ xA,
    short8* __restrict__ W1B, short8* __restrict__ W2B) {
  int blk = blockIdx.x, t = threadIdx.x;
  if (blk < 512) {
    int b = blk >> 4, w = blk & 15;
    const int* base = adj + (size_t)b * NN * NN + (size_t)w * 32 * NN;
#pragma unroll
    for (int half = 0; half < 2; ++half) {
      int d = t + half * 256;
      unsigned wv = 0;
#pragma unroll
      for (int j = 0; j < 32; ++j) {
        unsigned bit = ((base[(size_t)j * NN + d] != 0) || (w * 32 + j == d)) ? 1u : 0u;
        wv |= bit << j;
      }
      mask[((size_t)b * 16 + w) * NN + d] = wv;
    }
  } else if (blk < 1024) {
    int idx = (blk - 512) * 256 + t;
    int u = idx >> 6, lane = idx & 63;
    int b = u >> 6, mt = (u >> 2) & 15, kt = u & 3;
    int node = mt * 32 + (lane & 31);
    int k0 = kt * 16 + ((lane >> 5) << 3);
    const float* xp = x + ((size_t)b * NN + node) * 64 + k0;
    short8 r;
#pragma unroll
    for (int j = 0; j < 8; ++j) r[j] = (short)f2bf(xp[j]);
    xA[idx] = r;
  } else if (blk < 1033) {
    int idx = (blk - 1024) * 256 + t;  // 0..2303
    int unit = idx >> 6, lane = idx & 63;
    int nt = unit >> 2, kt = unit & 3;
    int k0 = kt * 16 + ((lane >> 5) << 3);
    short8 r;
    if (nt < 8) {
      int f = nt * 32 + (lane & 31);
#pragma unroll
      for (int j = 0; j < 8; ++j) r[j] = (short)f2bf(W1[(k0 + j) * 256 + f]);
    } else {  // e-tile: cols 0..3 = wa1_src heads, 4..7 = wa1_dst heads
      int c = lane & 31;
#pragma unroll
      for (int j = 0; j < 8; ++j) r[j] = 0;
      if (c < 8) {
        int h = c & 3;
        const float* av = ((c < 4) ? a1s : a1d) + h * 64;
#pragma unroll
        for (int j = 0; j < 8; ++j) {
          float s = 0.f;
          for (int f2 = 0; f2 < 64; ++f2)
            s += W1[(k0 + j) * 256 + h * 64 + f2] * av[f2];
          r[j] = (short)f2bf(s);
        }
      }
    }
    W1B[idx] = r;
  } else {
    int idx = (blk - 1033) * 256 + t;  // 0..3071
    int unit = idx >> 6, lane = idx & 63;
    int nt = unit >> 4, kt = unit & 15;
    int k0 = kt * 16 + ((lane >> 5) << 3);
    short8 r;
    if (nt < 2) {
      int f = nt * 32 + (lane & 31);
#pragma unroll
      for (int j = 0; j < 8; ++j) r[j] = (short)f2bf(W2[(k0 + j) * 64 + f]);
    } else {  // e-tile: col 0 = wa2_src, col 1 = wa2_dst
      int c = lane & 31;
#pragma unroll
      for (int j = 0; j < 8; ++j) r[j] = 0;
      if (c < 2) {
        const float* av = (c == 0) ? a2s : a2d;
#pragma unroll
        for (int j = 0; j < 8; ++j) {
          float s = 0.f;
          for (int f2 = 0; f2 < 64; ++f2) s += W2[(k0 + j) * 64 + f2] * av[f2];
          r[j] = (short)f2bf(s);
        }
      }
    }
    W2B[idx] = r;
  }
}

// ---------------- K2: h1 = x@W1 via MFMA -> hb1 B-frags; e-tile -> e1s/e1d
__global__ __launch_bounds__(64) void k_gemm1(const short8* __restrict__ xA,
                                              const short8* __restrict__ W1B,
                                              unsigned short* __restrict__ hb1,
                                              float* __restrict__ e1s,
                                              float* __restrict__ e1d) {
  __shared__ float tile[32 * 33];
  int b = blockIdx.x >> 4, mt = blockIdx.x & 15;
  int lane = threadIdx.x, m = lane & 31, kg = lane >> 5;
  short8 a[4];
#pragma unroll
  for (int kt = 0; kt < 4; ++kt)
    a[kt] = xA[((size_t)(b * 16 + mt) * 4 + kt) * 64 + lane];
  short8* hb8 = (short8*)hb1;
  for (int nt = 0; nt < 9; ++nt) {
    f32x16 acc;
#pragma unroll
    for (int i = 0; i < 16; ++i) acc[i] = 0.f;
#pragma unroll
    for (int kt = 0; kt < 4; ++kt)
      acc = __builtin_amdgcn_mfma_f32_32x32x16_bf16(
          a[kt], W1B[(nt * 4 + kt) * 64 + lane], acc, 0, 0, 0);
    if (nt < 8) {
#pragma unroll
      for (int reg = 0; reg < 16; ++reg) {
        int row = (reg & 3) + 8 * (reg >> 2) + 4 * kg;
        tile[row * 33 + m] = acc[reg];
      }
      __syncthreads();
      int h = nt >> 1, ft = nt & 1;
#pragma unroll
      for (int ktl = 0; ktl < 2; ++ktl) {
        short8 r;
#pragma unroll
        for (int j = 0; j < 8; ++j)
          r[j] = (short)f2bf(tile[(ktl * 16 + kg * 8 + j) * 33 + m]);
        hb8[((((size_t)b * 4 + h) * 32 + mt * 2 + ktl) * 2 + ft) * 64 + lane] = r;
      }
      __syncthreads();
    } else {
      if (m < 8) {
        float* p = ((m < 4) ? e1s : e1d) + ((size_t)b * 4 + (m & 3)) * NN + mt * 32;
#pragma unroll
        for (int reg = 0; reg < 16; ++reg) {
          int row = (reg & 3) + 8 * (reg >> 2) + 4 * kg;
          p[row] = acc[reg];
        }
      }
    }
  }
}

// ---------------- K3: layer-1 attention via MFMA; h1a emitted as bf16 A-frags for gemm2
__global__ __launch_bounds__(256) void k_attn1(const unsigned* __restrict__ mask,
                                               const unsigned short* __restrict__ hb1,
                                               const float* __restrict__ e1s,
                                               const float* __restrict__ e1d,
                                               const float* __restrict__ b1,
                                               short8* __restrict__ hA) {
  __shared__ float es[4 * NN];            // 8 KB
  __shared__ unsigned mw[16 * 32];        // 2 KB
  __shared__ unsigned short ht[32 * 264]; // 16.5 KB, pad 264 -> even b128 banks
  int b = blockIdx.x >> 4;
  int mt = blockIdx.x & 15;
  int d0 = mt * 32;
  int t = threadIdx.x;
  const float* esrc = e1s + (size_t)b * 4 * NN;
#pragma unroll
  for (int i = 0; i < 8; ++i) es[t + i * 256] = esrc[t + i * 256];
  const unsigned* msrc = mask + (size_t)b * 16 * NN + d0;
  mw[t] = msrc[(t >> 5) * NN + (t & 31)];
  {
    int idx = t + 256;
    mw[idx] = msrc[(idx >> 5) * NN + (idx & 31)];
  }
  __syncthreads();
  int h = t >> 6, lane = t & 63, m = lane & 31, kg = lane >> 5;
  float ed = e1d[((size_t)b * 4 + h) * NN + d0 + m];
  const short8* bfr = (const short8*)hb1 + ((size_t)b * 4 + h) * 32 * 2 * 64;
  f32x16 acc0, acc1;
#pragma unroll
  for (int i = 0; i < 16; ++i) { acc0[i] = 0.f; acc1[i] = 0.f; }
  float l = 0.f;
  for (int kt = 0; kt < 32; ++kt) {
    unsigned wv = mw[(kt >> 1) * 32 + m];
    int shift = (kt & 1) * 16 + kg * 8;
    const float* ep = &es[h * NN + kt * 16 + kg * 8];
    short8 a;
#pragma unroll
    for (int j = 0; j < 8; ++j) {
      float sc = ed + ep[j];
      sc = fmaxf(sc, NEG_SLOPE * sc);  // leaky_relu
      float pv = __expf(sc);           // scores O(+-8): no max-shift needed
      pv = ((wv >> (shift + j)) & 1u) ? pv : 0.f;
      l += pv;
      a[j] = (short)f2bf(pv);
    }
    short8 bv0 = bfr[(kt * 2 + 0) * 64 + lane];
    short8 bv1 = bfr[(kt * 2 + 1) * 64 + lane];
    acc0 = __builtin_amdgcn_mfma_f32_32x32x16_bf16(a, bv0, acc0, 0, 0, 0);
    acc1 = __builtin_amdgcn_mfma_f32_32x32x16_bf16(a, bv1, acc1, 0, 0, 0);
  }
  float lf = l + __shfl(l, lane ^ 32, 64);
  float linv = 1.f / lf;
  float bia0 = b1[h * 64 + m];
  float bia1 = b1[h * 64 + 32 + m];
#pragma unroll
  for (int reg = 0; reg < 16; ++reg) {
    int row = (reg & 3) + 8 * (reg >> 2) + 4 * kg;  // C/D row map (m74/m101)
    float li = __shfl(linv, row, 64);
    float v0 = acc0[reg] * li + bia0;
    v0 = (v0 > 0.f) ? v0 : (__expf(v0) - 1.f);  // ELU
    float v1 = acc1[reg] * li + bia1;
    v1 = (v1 > 0.f) ? v1 : (__expf(v1) - 1.f);
    ht[row * 264 + h * 64 + m] = f2bf(v0);
    ht[row * 264 + h * 64 + 32 + m] = f2bf(v1);
  }
  __syncthreads();
  // repack to gemm2 A-frags: lane holds node=lane&31, k = kt*16 + (lane>>5)*8 + j
  int lane2 = t & 63, w = t >> 6;
  int nl = lane2 & 31, kgo = (lane2 >> 5) * 8;
#pragma unroll
  for (int kk = 0; kk < 4; ++kk) {
    int kt = w * 4 + kk;
    short8 av = *(const short8*)&ht[nl * 264 + kt * 16 + kgo];
    hA[((size_t)(b * 16 + mt) * 16 + kt) * 64 + lane2] = av;
  }
}

// ---------------- K4: h2 = h1a@W2 via MFMA -> hb2 B-frags; e-tile -> e2s/e2d
__global__ __launch_bounds__(64) void k_gemm2(const short8* __restrict__ hA,
                                              const short8* __restrict__ W2B,
                                              unsigned short* __restrict__ hb2,
                                              float* __restrict__ e2s,
                                              float* __restrict__ e2d) {
  __shared__ float tile[32 * 33];
  int b = blockIdx.x >> 4, mt = blockIdx.x & 15;
  int lane = threadIdx.x, m = lane & 31, kg = lane >> 5;
  short8 a[16];
#pragma unroll
  for (int kt = 0; kt < 16; ++kt)
    a[kt] = hA[((size_t)(b * 16 + mt) * 16 + kt) * 64 + lane];
  short8* hb8 = (short8*)hb2;
  for (int nt = 0; nt < 3; ++nt) {
    f32x16 acc;
#pragma unroll
    for (int i = 0; i < 16; ++i) acc[i] = 0.f;
#pragma unroll
    for (int kt = 0; kt < 16; ++kt)
      acc = __builtin_amdgcn_mfma_f32_32x32x16_bf16(
          a[kt], W2B[(nt * 16 + kt) * 64 + lane], acc, 0, 0, 0);
    if (nt < 2) {
#pragma unroll
      for (int reg = 0; reg < 16; ++reg) {
        int row = (reg & 3) + 8 * (reg >> 2) + 4 * kg;
        tile[row * 33 + m] = acc[reg];
      }
      __syncthreads();
#pragma unroll
      for (int ktl = 0; ktl < 2; ++ktl) {
        short8 r;
#pragma unroll
        for (int j = 0; j < 8; ++j)
          r[j] = (short)f2bf(tile[(ktl * 16 + kg * 8 + j) * 33 + m]);
        hb8[(((size_t)b * 32 + mt * 2 + ktl) * 2 + nt) * 64 + lane] = r;
      }
      __syncthreads();
    } else {
      if (m < 2) {
        float* p = ((m == 0) ? e2s : e2d) + (size_t)b * NN + mt * 32;
#pragma unroll
        for (int reg = 0; reg < 16; ++reg) {
          int row = (reg & 3) + 8 * (reg >> 2) + 4 * kg;
          p[row] = acc[reg];
        }
      }
    }
  }
}

// ---------------- K5: layer-2 attention via MFMA, 4 waves split K, LDS reduce
__global__ __launch_bounds__(256) void k_attn2(const unsigned* __restrict__ mask,
                                               const unsigned short* __restrict__ hb2,
                                               const float* __restrict__ e2s,
                                               const float* __restrict__ e2d,
                                               const float* __restrict__ b2,
                                               float* __restrict__ out) {
  __shared__ float es[NN];
  __shared__ unsigned mw[16 * 32];
  __shared__ float cred[4][2][16][64];
  __shared__ float lred[4][64];
  __shared__ float linv_s[32];
  int b = blockIdx.x >> 4;
  int d0 = (blockIdx.x & 15) * 32;
  int t = threadIdx.x;
  es[t] = e2s[(size_t)b * NN + t];
  es[t + 256] = e2s[(size_t)b * NN + t + 256];
  const unsigned* msrc = mask + (size_t)b * 16 * NN + d0;
  mw[t] = msrc[(t >> 5) * NN + (t & 31)];
  {
    int idx = t + 256;
    mw[idx] = msrc[(idx >> 5) * NN + (idx & 31)];
  }
  __syncthreads();
  int w = t >> 6, lane = t & 63, m = lane & 31, kg = lane >> 5;
  float ed = e2d[(size_t)b * NN + d0 + m];
  const short8* bfr = (const short8*)hb2 + (size_t)b * 32 * 2 * 64;
  f32x16 acc0, acc1;
#pragma unroll
  for (int i = 0; i < 16; ++i) { acc0[i] = 0.f; acc1[i] = 0.f; }
  float l = 0.f;
#pragma unroll
  for (int kk = 0; kk < 8; ++kk) {
    int kt = w * 8 + kk;
    unsigned wv = mw[(kt >> 1) * 32 + m];
    int shift = (kt & 1) * 16 + kg * 8;
    const float* ep = &es[kt * 16 + kg * 8];
    short8 a;
#pragma unroll
    for (int j = 0; j < 8; ++j) {
      float sc = ed + ep[j];
      sc = fmaxf(sc, NEG_SLOPE * sc);
      float pv = __expf(sc);
      pv = ((wv >> (shift + j)) & 1u) ? pv : 0.f;
      l += pv;
      a[j] = (short)f2bf(pv);
    }
    short8 bv0 = bfr[(kt * 2 + 0) * 64 + lane];
    short8 bv1 = bfr[(kt * 2 + 1) * 64 + lane];
    acc0 = __builtin_amdgcn_mfma_f32_32x32x16_bf16(a, bv0, acc0, 0, 0, 0);
    acc1 = __builtin_amdgcn_mfma_f32_32x32x16_bf16(a, bv1, acc1, 0, 0, 0);
  }
  lred[w][lane] = l;
#pragma unroll
  for (int reg = 0; reg < 16; ++reg) {
    cred[w][0][reg][lane] = acc0[reg];
    cred[w][1][reg][lane] = acc1[reg];
  }
  __syncthreads();
  if (t < 32) {
    float s = 0.f;
#pragma unroll
    for (int i = 0; i < 4; ++i) s += lred[i][t] + lred[i][t + 32];
    linv_s[t] = 1.f / s;
  }
  __syncthreads();
#pragma unroll
  for (int i = 0; i < 8; ++i) {
    int pos = t + i * 256;
    int nt = pos >> 10;
    int rem = pos & 1023;
    int reg = rem >> 6;
    int ln = rem & 63;
    float v = cred[0][nt][reg][ln] + cred[1][nt][reg][ln] +
              cred[2][nt][reg][ln] + cred[3][nt][reg][ln];
    int row = (reg & 3) + 8 * (reg >> 2) + 4 * (ln >> 5);
    int col = nt * 32 + (ln & 31);
    out[((size_t)b * NN + d0 + row) * 64 + col] = v * linv_s[row] + b2[col];
  }
}

extern "C" void kernel_launch(void* const* d_in, const int* in_sizes, int n_in,
                              void* d_out, int out_size, void* d_ws, size_t ws_size,
                              hipStream_t stream) {
  const float* x = (const float*)d_in[0];
  const int* adj = (const int*)d_in[1];
  const float* W1 = (const float*)d_in[2];
  const float* a1s = (const float*)d_in[3];
  const float* a1d = (const float*)d_in[4];
  const float* b1 = (const float*)d_in[5];
  const float* W2 = (const float*)d_in[6];
  const float* a2s = (const float*)d_in[7];
  const float* a2d = (const float*)d_in[8];
  const float* b2 = (const float*)d_in[9];
  float* out = (float*)d_out;

  char* w = (char*)d_ws;
  unsigned* mask = (unsigned*)w;                                 // 1 MiB
  short8* xA = (short8*)(w + (1u << 20));                        // 2 MiB
  short8* W1B = (short8*)(w + (3u << 20));                       // 36 KiB
  short8* W2B = (short8*)(w + (3u << 20) + (64u << 10));         // 48 KiB
  unsigned short* hb1 = (unsigned short*)(w + (4u << 20));       // 8 MiB
  float* e1s = (float*)(w + (12u << 20));                        // 256 KiB
  float* e1d = (float*)(w + (12u << 20) + (256u << 10));         // 256 KiB
  short8* hA = (short8*)(w + (13u << 20));                       // 8 MiB
  unsigned short* hb2 = (unsigned short*)(w + (21u << 20));      // 2 MiB
  float* e2s = (float*)(w + (23u << 20));                        // 64 KiB
  float* e2d = (float*)(w + (23u << 20) + (64u << 10));          // 64 KiB

  hipLaunchKernelGGL(k_prep, dim3(1045), dim3(256), 0, stream, adj, x, W1, a1s,
                     a1d, W2, a2s, a2d, mask, xA, W1B, W2B);
  hipLaunchKernelGGL(k_gemm1, dim3(512), dim3(64), 0, stream, xA, W1B, hb1,
                     e1s, e1d);
  hipLaunchKernelGGL(k_attn1, dim3(512), dim3(256), 0, stream, mask, hb1, e1s,
                     e1d, b1, hA);
  hipLaunchKernelGGL(k_gemm2, dim3(512), dim3(64), 0, stream, hA, W2B, hb2,
                     e2s, e2d);
  hipLaunchKernelGGL(k_attn2, dim3(512), dim3(256), 0, stream, mask, hb2, e2s,
                     e2d, b2, out);
}

// Round 4
// 133.251 us; speedup vs baseline: 3.5236x; 1.1061x over previous
//
#include <hip/hip_runtime.h>
#include <cstddef>

#define NN 512
#define NEG_SLOPE 0.2f

typedef __attribute__((ext_vector_type(8))) short short8;
typedef __attribute__((ext_vector_type(16))) float f32x16;

__device__ __forceinline__ unsigned short f2bf(float v) {
  unsigned u = __float_as_uint(v);
  return (unsigned short)((u + 0x7FFFu + ((u >> 16) & 1u)) >> 16);
}

// ---------------- K0: prep. blocks 0..511: adj->bitmask;
// 512..520: W1(+wa1)->B-frags; 521..532: W2(+wa2)->B-frags
__global__ __launch_bounds__(256) void k_prep(
    const int* __restrict__ adj, const float* __restrict__ W1,
    const float* __restrict__ a1s, const float* __restrict__ a1d,
    const float* __restrict__ W2, const float* __restrict__ a2s,
    const float* __restrict__ a2d, unsigned* __restrict__ mask,
    short8* __restrict__ W1B, short8* __restrict__ W2B) {
  int blk = blockIdx.x, t = threadIdx.x;
  if (blk < 512) {
    int b = blk >> 4, w = blk & 15;
    const int* base = adj + (size_t)b * NN * NN + (size_t)w * 32 * NN;
#pragma unroll
    for (int half = 0; half < 2; ++half) {
      int d = t + half * 256;
      unsigned wv = 0;
#pragma unroll
      for (int j = 0; j < 32; ++j) {
        unsigned bit = ((base[(size_t)j * NN + d] != 0) || (w * 32 + j == d)) ? 1u : 0u;
        wv |= bit << j;
      }
      mask[((size_t)b * 16 + w) * NN + d] = wv;
    }
  } else if (blk < 521) {
    int blk2 = blk - 512;
    if (blk2 < 8) {  // W1 feature tiles nt 0..7
      int idx = blk2 * 256 + t;
      int unit = idx >> 6, lane = idx & 63;
      int nt = unit >> 2, kt = unit & 3;
      int f = nt * 32 + (lane & 31);
      int k0 = kt * 16 + ((lane >> 5) << 3);
      short8 r;
#pragma unroll
      for (int j = 0; j < 8; ++j) r[j] = (short)f2bf(W1[(k0 + j) * 256 + f]);
      W1B[idx] = r;
    } else {  // e-tile (nt=8): cols 0..3 wa1_src heads, 4..7 wa1_dst heads
      __shared__ float wa1[64][8];
#pragma unroll
      for (int rep = 0; rep < 2; ++rep) {
        int id = t + rep * 256;
        int k = id >> 3, c = id & 7, h = c & 3;
        const float* av = ((c < 4) ? a1s : a1d) + h * 64;
        float s = 0.f;
        for (int f2 = 0; f2 < 64; ++f2) s += W1[k * 256 + h * 64 + f2] * av[f2];
        wa1[k][c] = s;
      }
      __syncthreads();
      int kt = t >> 6, lane = t & 63, col = lane & 31, kg = lane >> 5;
      short8 r;
#pragma unroll
      for (int j = 0; j < 8; ++j)
        r[j] = (col < 8) ? (short)f2bf(wa1[kt * 16 + kg * 8 + j][col]) : (short)0;
      W1B[2048 + t] = r;
    }
  } else {
    int blk3 = blk - 521;
    if (blk3 < 8) {  // W2 feature tiles nt 0..1
      int idx = blk3 * 256 + t;
      int unit = idx >> 6, lane = idx & 63;
      int nt = unit >> 4, kt = unit & 15;
      int f = nt * 32 + (lane & 31);
      int k0 = kt * 16 + ((lane >> 5) << 3);
      short8 r;
#pragma unroll
      for (int j = 0; j < 8; ++j) r[j] = (short)f2bf(W2[(k0 + j) * 64 + f]);
      W2B[idx] = r;
    } else {  // e-tile (nt=2), 4 blocks covering k in [ (blk3-8)*64, +64 )
      __shared__ float wa2[64][2];
      int kbase = (blk3 - 8) * 64;
      if (t < 128) {
        int k = t >> 1, c = t & 1;
        const float* av = (c == 0) ? a2s : a2d;
        float s = 0.f;
        for (int f2 = 0; f2 < 64; ++f2) s += W2[(kbase + k) * 64 + f2] * av[f2];
        wa2[k][c] = s;
      }
      __syncthreads();
      int ktl = t >> 6, lane = t & 63, col = lane & 31, kg = lane >> 5;
      short8 r;
#pragma unroll
      for (int j = 0; j < 8; ++j)
        r[j] = (col < 2) ? (short)f2bf(wa2[ktl * 16 + kg * 8 + j][col]) : (short)0;
      W2B[2048 + (blk3 - 8) * 256 + t] = r;
    }
  }
}

// ---------------- K2: h1 = x@W1 via MFMA (x packed in-register) -> hb1 B-frags; e1
__global__ __launch_bounds__(64) void k_gemm1(const float* __restrict__ x,
                                              const short8* __restrict__ W1B,
                                              unsigned short* __restrict__ hb1,
                                              float* __restrict__ e1s,
                                              float* __restrict__ e1d) {
  __shared__ float tile[32 * 33];
  int i = blockIdx.x;
  int b = (i & 7) * 4 + ((i >> 3) & 3), mt = i >> 5;  // XCD-affine swizzle
  int lane = threadIdx.x, m = lane & 31, kg = lane >> 5;
  const float* xrow = x + ((size_t)b * NN + mt * 32 + m) * 64 + kg * 8;
  short8 a[4];
#pragma unroll
  for (int kt = 0; kt < 4; ++kt) {
    float4 v0 = *(const float4*)(xrow + kt * 16);
    float4 v1 = *(const float4*)(xrow + kt * 16 + 4);
    short8 r;
    r[0] = (short)f2bf(v0.x); r[1] = (short)f2bf(v0.y);
    r[2] = (short)f2bf(v0.z); r[3] = (short)f2bf(v0.w);
    r[4] = (short)f2bf(v1.x); r[5] = (short)f2bf(v1.y);
    r[6] = (short)f2bf(v1.z); r[7] = (short)f2bf(v1.w);
    a[kt] = r;
  }
  short8* hb8 = (short8*)hb1;
  for (int nt = 0; nt < 9; ++nt) {
    f32x16 acc;
#pragma unroll
    for (int q = 0; q < 16; ++q) acc[q] = 0.f;
#pragma unroll
    for (int kt = 0; kt < 4; ++kt)
      acc = __builtin_amdgcn_mfma_f32_32x32x16_bf16(
          a[kt], W1B[(nt * 4 + kt) * 64 + lane], acc, 0, 0, 0);
    if (nt < 8) {
#pragma unroll
      for (int reg = 0; reg < 16; ++reg) {
        int row = (reg & 3) + 8 * (reg >> 2) + 4 * kg;
        tile[row * 33 + m] = acc[reg];
      }
      __syncthreads();
      int h = nt >> 1, ft = nt & 1;
#pragma unroll
      for (int ktl = 0; ktl < 2; ++ktl) {
        short8 r;
#pragma unroll
        for (int j = 0; j < 8; ++j)
          r[j] = (short)f2bf(tile[(ktl * 16 + kg * 8 + j) * 33 + m]);
        hb8[((((size_t)b * 4 + h) * 32 + mt * 2 + ktl) * 2 + ft) * 64 + lane] = r;
      }
      __syncthreads();
    } else {
      if (m < 8) {
        float* p = ((m < 4) ? e1s : e1d) + ((size_t)b * 4 + (m & 3)) * NN + mt * 32;
#pragma unroll
        for (int reg = 0; reg < 16; ++reg) {
          int row = (reg & 3) + 8 * (reg >> 2) + 4 * kg;
          p[row] = acc[reg];
        }
      }
    }
  }
}

// ---------------- K3: fused layer-1 attention + layer-2 GEMM.
// Waves = heads for attn; then waves 0..2 run the 3 n-tiles of h1a@W2 from LDS.
__global__ __launch_bounds__(256) void k_attn1g2(const unsigned* __restrict__ mask,
                                                 const unsigned short* __restrict__ hb1,
                                                 const float* __restrict__ e1s,
                                                 const float* __restrict__ e1d,
                                                 const float* __restrict__ b1,
                                                 const short8* __restrict__ W2B,
                                                 unsigned short* __restrict__ hb2,
                                                 float* __restrict__ e2s,
                                                 float* __restrict__ e2d) {
  __shared__ float es[4 * NN];             // 8 KB
  __shared__ unsigned mw[16 * 32];         // 2 KB
  __shared__ unsigned short ht[32 * 264];  // 16.5 KB (row stride 264 = 33*16B)
  __shared__ float tile2[2 * 32 * 33];     // 8.4 KB
  int i = blockIdx.x;
  int b = (i & 7) * 4 + ((i >> 3) & 3), mt = i >> 5;  // XCD-affine swizzle
  int d0 = mt * 32;
  int t = threadIdx.x;
  const float* esrc = e1s + (size_t)b * 4 * NN;
#pragma unroll
  for (int q = 0; q < 8; ++q) es[t + q * 256] = esrc[t + q * 256];
  const unsigned* msrc = mask + (size_t)b * 16 * NN + d0;
  mw[t] = msrc[(t >> 5) * NN + (t & 31)];
  {
    int idx = t + 256;
    mw[idx] = msrc[(idx >> 5) * NN + (idx & 31)];
  }
  __syncthreads();
  int h = t >> 6, lane = t & 63, m = lane & 31, kg = lane >> 5;
  float ed = e1d[((size_t)b * 4 + h) * NN + d0 + m];
  const short8* bfr = (const short8*)hb1 + ((size_t)b * 4 + h) * 32 * 2 * 64;
  f32x16 acc0, acc1;
#pragma unroll
  for (int q = 0; q < 16; ++q) { acc0[q] = 0.f; acc1[q] = 0.f; }
  float l = 0.f;
  for (int kt = 0; kt < 32; ++kt) {
    unsigned wv = mw[(kt >> 1) * 32 + m];
    int shift = (kt & 1) * 16 + kg * 8;
    const float* ep = &es[h * NN + kt * 16 + kg * 8];
    short8 a;
#pragma unroll
    for (int j = 0; j < 8; ++j) {
      float sc = ed + ep[j];
      sc = fmaxf(sc, NEG_SLOPE * sc);  // leaky_relu
      float pv = __expf(sc);           // scores O(+-8): no max-shift needed
      pv = ((wv >> (shift + j)) & 1u) ? pv : 0.f;
      l += pv;
      a[j] = (short)f2bf(pv);
    }
    short8 bv0 = bfr[(kt * 2 + 0) * 64 + lane];
    short8 bv1 = bfr[(kt * 2 + 1) * 64 + lane];
    acc0 = __builtin_amdgcn_mfma_f32_32x32x16_bf16(a, bv0, acc0, 0, 0, 0);
    acc1 = __builtin_amdgcn_mfma_f32_32x32x16_bf16(a, bv1, acc1, 0, 0, 0);
  }
  float lf = l + __shfl(l, lane ^ 32, 64);
  float linv = 1.f / lf;
  float bia0 = b1[h * 64 + m];
  float bia1 = b1[h * 64 + 32 + m];
#pragma unroll
  for (int reg = 0; reg < 16; ++reg) {
    int row = (reg & 3) + 8 * (reg >> 2) + 4 * kg;  // C/D row map (m74/m101)
    float li = __shfl(linv, row, 64);
    float v0 = acc0[reg] * li + bia0;
    v0 = (v0 > 0.f) ? v0 : (__expf(v0) - 1.f);  // ELU
    float v1 = acc1[reg] * li + bia1;
    v1 = (v1 > 0.f) ? v1 : (__expf(v1) - 1.f);
    ht[row * 264 + h * 64 + m] = f2bf(v0);
    ht[row * 264 + h * 64 + 32 + m] = f2bf(v1);
  }
  __syncthreads();
  // ---- fused gemm2: h2 = h1a@W2 for this block's 32 nodes, A-frags from ht
  int w2 = t >> 6, lane2 = t & 63, m2 = lane2 & 31, kg2 = lane2 >> 5;
  if (w2 < 3) {
    int nt = w2;
    f32x16 acc;
#pragma unroll
    for (int q = 0; q < 16; ++q) acc[q] = 0.f;
#pragma unroll
    for (int kt = 0; kt < 16; ++kt) {
      short8 av = *(const short8*)&ht[m2 * 264 + kt * 16 + kg2 * 8];
      acc = __builtin_amdgcn_mfma_f32_32x32x16_bf16(
          av, W2B[(nt * 16 + kt) * 64 + lane2], acc, 0, 0, 0);
    }
    if (nt < 2) {
      float* tw = tile2 + nt * (32 * 33);
#pragma unroll
      for (int reg = 0; reg < 16; ++reg) {
        int row = (reg & 3) + 8 * (reg >> 2) + 4 * kg2;
        tw[row * 33 + m2] = acc[reg];
      }
      short8* hb8 = (short8*)hb2;
#pragma unroll
      for (int ktl = 0; ktl < 2; ++ktl) {
        short8 r;
#pragma unroll
        for (int j = 0; j < 8; ++j)
          r[j] = (short)f2bf(tw[(ktl * 16 + kg2 * 8 + j) * 33 + m2]);
        hb8[(((size_t)b * 32 + mt * 2 + ktl) * 2 + nt) * 64 + lane2] = r;
      }
    } else {
      if (m2 < 2) {
        float* p = ((m2 == 0) ? e2s : e2d) + (size_t)b * NN + mt * 32;
#pragma unroll
        for (int reg = 0; reg < 16; ++reg) {
          int row = (reg & 3) + 8 * (reg >> 2) + 4 * kg2;
          p[row] = acc[reg];
        }
      }
    }
  }
}

// ---------------- K5: layer-2 attention via MFMA, 4 waves split K, LDS reduce
__global__ __launch_bounds__(256) void k_attn2(const unsigned* __restrict__ mask,
                                               const unsigned short* __restrict__ hb2,
                                               const float* __restrict__ e2s,
                                               const float* __restrict__ e2d,
                                               const float* __restrict__ b2,
                                               float* __restrict__ out) {
  __shared__ float es[NN];
  __shared__ unsigned mw[16 * 32];
  __shared__ float cred[4][2][16][64];
  __shared__ float lred[4][64];
  __shared__ float linv_s[32];
  int i = blockIdx.x;
  int b = (i & 7) * 4 + ((i >> 3) & 3);  // XCD-affine swizzle
  int d0 = (i >> 5) * 32;
  int t = threadIdx.x;
  es[t] = e2s[(size_t)b * NN + t];
  es[t + 256] = e2s[(size_t)b * NN + t + 256];
  const unsigned* msrc = mask + (size_t)b * 16 * NN + d0;
  mw[t] = msrc[(t >> 5) * NN + (t & 31)];
  {
    int idx = t + 256;
    mw[idx] = msrc[(idx >> 5) * NN + (idx & 31)];
  }
  __syncthreads();
  int w = t >> 6, lane = t & 63, m = lane & 31, kg = lane >> 5;
  float ed = e2d[(size_t)b * NN + d0 + m];
  const short8* bfr = (const short8*)hb2 + (size_t)b * 32 * 2 * 64;
  f32x16 acc0, acc1;
#pragma unroll
  for (int q = 0; q < 16; ++q) { acc0[q] = 0.f; acc1[q] = 0.f; }
  float l = 0.f;
#pragma unroll
  for (int kk = 0; kk < 8; ++kk) {
    int kt = w * 8 + kk;
    unsigned wv = mw[(kt >> 1) * 32 + m];
    int shift = (kt & 1) * 16 + kg * 8;
    const float* ep = &es[kt * 16 + kg * 8];
    short8 a;
#pragma unroll
    for (int j = 0; j < 8; ++j) {
      float sc = ed + ep[j];
      sc = fmaxf(sc, NEG_SLOPE * sc);
      float pv = __expf(sc);
      pv = ((wv >> (shift + j)) & 1u) ? pv : 0.f;
      l += pv;
      a[j] = (short)f2bf(pv);
    }
    short8 bv0 = bfr[(kt * 2 + 0) * 64 + lane];
    short8 bv1 = bfr[(kt * 2 + 1) * 64 + lane];
    acc0 = __builtin_amdgcn_mfma_f32_32x32x16_bf16(a, bv0, acc0, 0, 0, 0);
    acc1 = __builtin_amdgcn_mfma_f32_32x32x16_bf16(a, bv1, acc1, 0, 0, 0);
  }
  lred[w][lane] = l;
#pragma unroll
  for (int reg = 0; reg < 16; ++reg) {
    cred[w][0][reg][lane] = acc0[reg];
    cred[w][1][reg][lane] = acc1[reg];
  }
  __syncthreads();
  if (t < 32) {
    float s = 0.f;
#pragma unroll
    for (int q = 0; q < 4; ++q) s += lred[q][t] + lred[q][t + 32];
    linv_s[t] = 1.f / s;
  }
  __syncthreads();
#pragma unroll
  for (int q = 0; q < 8; ++q) {
    int pos = t + q * 256;
    int nt = pos >> 10;
    int rem = pos & 1023;
    int reg = rem >> 6;
    int ln = rem & 63;
    float v = cred[0][nt][reg][ln] + cred[1][nt][reg][ln] +
              cred[2][nt][reg][ln] + cred[3][nt][reg][ln];
    int row = (reg & 3) + 8 * (reg >> 2) + 4 * (ln >> 5);
    int col = nt * 32 + (ln & 31);
    out[((size_t)b * NN + d0 + row) * 64 + col] = v * linv_s[row] + b2[col];
  }
}

extern "C" void kernel_launch(void* const* d_in, const int* in_sizes, int n_in,
                              void* d_out, int out_size, void* d_ws, size_t ws_size,
                              hipStream_t stream) {
  const float* x = (const float*)d_in[0];
  const int* adj = (const int*)d_in[1];
  const float* W1 = (const float*)d_in[2];
  const float* a1s = (const float*)d_in[3];
  const float* a1d = (const float*)d_in[4];
  const float* b1 = (const float*)d_in[5];
  const float* W2 = (const float*)d_in[6];
  const float* a2s = (const float*)d_in[7];
  const float* a2d = (const float*)d_in[8];
  const float* b2 = (const float*)d_in[9];
  float* out = (float*)d_out;

  char* w = (char*)d_ws;
  unsigned* mask = (unsigned*)w;                             // 1 MiB
  short8* W1B = (short8*)(w + (3u << 20));                   // 36 KiB
  short8* W2B = (short8*)(w + (3u << 20) + (64u << 10));     // 48 KiB
  unsigned short* hb1 = (unsigned short*)(w + (4u << 20));   // 8 MiB
  float* e1s = (float*)(w + (12u << 20));                    // 256 KiB
  float* e1d = (float*)(w + (12u << 20) + (256u << 10));     // 256 KiB
  unsigned short* hb2 = (unsigned short*)(w + (21u << 20));  // 2 MiB
  float* e2s = (float*)(w + (23u << 20));                    // 64 KiB
  float* e2d = (float*)(w + (23u << 20) + (64u << 10));      // 64 KiB

  hipLaunchKernelGGL(k_prep, dim3(533), dim3(256), 0, stream, adj, W1, a1s,
                     a1d, W2, a2s, a2d, mask, W1B, W2B);
  hipLaunchKernelGGL(k_gemm1, dim3(512), dim3(64), 0, stream, x, W1B, hb1,
                     e1s, e1d);
  hipLaunchKernelGGL(k_attn1g2, dim3(512), dim3(256), 0, stream, mask, hb1,
                     e1s, e1d, b1, W2B, hb2, e2s, e2d);
  hipLaunchKernelGGL(k_attn2, dim3(512), dim3(256), 0, stream, mask, hb2, e2s,
                     e2d, b2, out);
}